// Round 1
// baseline (3184.392 us; speedup 1.0000x reference)
//
#include <hip/hip_runtime.h>

#define NN 50000
#define NG 100
#define NPG 500
#define NE 800000
#define EPG 8000
#define EMBD 128
#define NL 4

typedef __attribute__((ext_vector_type(8))) short short8v;
typedef __attribute__((ext_vector_type(4))) float float4v;

__device__ __forceinline__ unsigned short f2bf(float v) {
  unsigned u = __float_as_uint(v);
  u += 0x7FFFu + ((u >> 16) & 1u);
  return (unsigned short)(u >> 16);
}
__device__ __forceinline__ float bf2f(unsigned short h) {
  return __uint_as_float(((unsigned)h) << 16);
}

// ---------------- Wcat^T (bf16) prep: whT[l][cc][k], cc = m*128+c ----------------
// m=0: Wf rows k (x_i part); m=1: Wf rows 128+k (x_j); m=2: Ws rows k; m=3: Ws rows 128+k
__global__ void prep_w(const float* __restrict__ Wf, const float* __restrict__ Ws,
                       unsigned short* __restrict__ whT) {
  int idx = blockIdx.x * 256 + threadIdx.x;   // 4*512*128 = 262144
  int k = idx & 127;
  int cc = (idx >> 7) & 511;
  int l = idx >> 16;
  int m = cc >> 7, c = cc & 127;
  const float* W = (m < 2) ? Wf : Ws;
  int row = ((m & 1) << 7) + k;
  whT[idx] = f2bf(W[(size_t)l * 32896 + (size_t)row * 128 + c]);
}

// ---------------- x0 = emb[z] ----------------
__global__ void gather_x(const float* __restrict__ emb, const int* __restrict__ z,
                         float* __restrict__ x, unsigned short* __restrict__ xh) {
  const int total = NN * 32;
  for (int idx = blockIdx.x * 256 + threadIdx.x; idx < total; idx += gridDim.x * 256) {
    int n = idx >> 5, c4 = (idx & 31) * 4;
    float4 v = *(const float4*)(emb + (size_t)z[n] * EMBD + c4);
    size_t base = (size_t)idx * 4;
    *(float4*)(x + base) = v;
    ushort4 h;
    h.x = f2bf(v.x); h.y = f2bf(v.y); h.z = f2bf(v.z); h.w = f2bf(v.w);
    *(ushort4*)(xh + base) = h;
  }
}

// ---------------- per-edge distance ----------------
__global__ void edge_dist(const float* __restrict__ pos, const int* __restrict__ ei,
                          float* __restrict__ dist) {
  for (int e = blockIdx.x * 256 + threadIdx.x; e < NE; e += gridDim.x * 256) {
    int j = ei[e], i = ei[NE + e];
    float dx = pos[i * 3 + 0] - pos[j * 3 + 0];
    float dy = pos[i * 3 + 1] - pos[j * 3 + 1];
    float dz = pos[i * 3 + 2] - pos[j * 3 + 2];
    dist[e] = sqrtf(dx * dx + dy * dy + dz * dz);
  }
}

// ---------------- P[n][512] = x(bf16) @ Wcat (MFMA 16x16x32 bf16) ----------------
#define BM 128
#define BN 64
__global__ __launch_bounds__(256, 3) void gemm_proj(const unsigned short* __restrict__ xh,
                                                    const unsigned short* __restrict__ whT,
                                                    unsigned short* __restrict__ P, int l) {
  __shared__ __align__(16) unsigned short sA[BM * 128];  // 32KB, XOR-swizzled granules
  __shared__ __align__(16) unsigned short sB[BN * 128];  // 16KB
  const int tid = threadIdx.x;
  const int R0 = blockIdx.x * BM;
  const int C0 = blockIdx.y * BN;
  // stage A: BM rows x 16 granules(16B = 8 bf16)
  for (int gid = tid; gid < BM * 16; gid += 256) {
    int row = gid >> 4, gc = gid & 15;
    int grow = R0 + row;
    uint4 v = make_uint4(0u, 0u, 0u, 0u);
    if (grow < NN) v = *(const uint4*)(xh + (size_t)grow * 128 + gc * 8);
    int gs = (gc & 8) | ((gc ^ row) & 7);
    *(uint4*)((char*)sA + row * 256 + gs * 16) = v;
  }
  // stage B (already transposed): BN cols x 16 granules
  for (int gid = tid; gid < BN * 16; gid += 256) {
    int c = gid >> 4, gc = gid & 15;
    uint4 v = *(const uint4*)(whT + ((size_t)l * 512 + C0 + c) * 128 + gc * 8);
    int gs = (gc & 8) | ((gc ^ c) & 7);
    *(uint4*)((char*)sB + c * 256 + gs * 16) = v;
  }
  __syncthreads();
  const int w = tid >> 6, lane = tid & 63;
  const int lr = lane & 15, lk = lane >> 4;  // lr: row/col in frag, lk: k-group
  float4v acc[2][4];
#pragma unroll
  for (int i = 0; i < 2; i++)
#pragma unroll
    for (int j = 0; j < 4; j++) acc[i][j] = (float4v){0.f, 0.f, 0.f, 0.f};
#pragma unroll
  for (int kb = 0; kb < 4; kb++) {
    int g = kb * 4 + lk;
    short8v a[2], b[4];
#pragma unroll
    for (int rf = 0; rf < 2; rf++) {
      int row = w * 32 + rf * 16 + lr;
      int gs = (g & 8) | ((g ^ row) & 7);
      a[rf] = *(const short8v*)((const char*)sA + row * 256 + gs * 16);
    }
#pragma unroll
    for (int cf = 0; cf < 4; cf++) {
      int c = cf * 16 + lr;
      int gs = (g & 8) | ((g ^ c) & 7);
      b[cf] = *(const short8v*)((const char*)sB + c * 256 + gs * 16);
    }
#pragma unroll
    for (int rf = 0; rf < 2; rf++)
#pragma unroll
      for (int cf = 0; cf < 4; cf++)
        acc[rf][cf] = __builtin_amdgcn_mfma_f32_16x16x32_bf16(a[rf], b[cf], acc[rf][cf], 0, 0, 0);
  }
  // store (C/D: col = lane&15, row = (lane>>4)*4 + j) — verified layout
#pragma unroll
  for (int rf = 0; rf < 2; rf++) {
#pragma unroll
    for (int cf = 0; cf < 4; cf++) {
      int col = C0 + cf * 16 + lr;
#pragma unroll
      for (int j = 0; j < 4; j++) {
        int row = R0 + w * 32 + rf * 16 + lk * 4 + j;
        if (row < NN) P[(size_t)row * 512 + col] = f2bf(acc[rf][cf][j]);
      }
    }
  }
}

// ---------------- edge pass: msg = sigmoid(f)*softplus(s), LDS segment-sum ----------------
__global__ __launch_bounds__(512, 2) void edge_pass(const unsigned short* __restrict__ P,
                                                    const float* __restrict__ dist,
                                                    const int* __restrict__ ei,
                                                    const float* __restrict__ Wf,
                                                    const float* __restrict__ bf,
                                                    const float* __restrict__ Ws,
                                                    const float* __restrict__ bs,
                                                    float* __restrict__ agg, int l) {
  __shared__ float sAgg[NPG * 32];  // 64 KB
  const int blk = blockIdx.x;       // 400 = graph*4 + fsplit
  const int g = blk >> 2, fs = blk & 3;
  const int fbase = fs * 32;
  const int tid = threadIdx.x;
  for (int t = tid; t < NPG * 32; t += 512) sAgg[t] = 0.f;
  const int lane = tid & 31, grp = tid >> 5;  // 16 groups of 32
  const int f = fbase + lane;
  const float wfd = Wf[(size_t)l * 32896 + 256 * 128 + f];
  const float bfv = bf[l * 128 + f];
  const float wsd = Ws[(size_t)l * 32896 + 256 * 128 + f];
  const float bsv = bs[l * 128 + f];
  __syncthreads();
  const int ebase = g * EPG;
#pragma unroll 4
  for (int it = 0; it < EPG / 16; it++) {
    int e = ebase + it * 16 + grp;
    int j = ei[e], i = ei[NE + e];
    float dv = dist[e];
    const unsigned short* Pi = P + (size_t)i * 512;
    const unsigned short* Pj = P + (size_t)j * 512;
    float pf = bf2f(Pi[f]) + bf2f(Pj[128 + f]) + dv * wfd + bfv;
    float ps = bf2f(Pi[256 + f]) + bf2f(Pj[384 + f]) + dv * wsd + bsv;
    float sig = 1.f / (1.f + __expf(-pf));
    float sp = fmaxf(ps, 0.f) + log1pf(__expf(-fabsf(ps)));
    int il = i - g * NPG;
    if ((unsigned)il < (unsigned)NPG) atomicAdd(&sAgg[il * 32 + lane], sig * sp);
  }
  __syncthreads();
  for (int t = tid; t < NPG * 32; t += 512) {
    int row = t >> 5, ff = t & 31;
    agg[(size_t)(g * NPG + row) * EMBD + fbase + ff] = sAgg[t];
  }
}

// ---------------- per-column partial sums for both BNs ----------------
__global__ void col_stats(const float* __restrict__ agg, const float* __restrict__ x,
                          float* __restrict__ partial) {
  const int b = blockIdx.x, tid = threadIdx.x;
  const int c = tid & 127, h = tid >> 7;  // 0..1
  float sa = 0, sa2 = 0, sx = 0, sx2 = 0, sax = 0;
  int r0 = b * 250;
  for (int rr = h; rr < 250; rr += 2) {
    size_t idx = (size_t)(r0 + rr) * EMBD + c;
    float a = agg[idx], xv = x[idx];
    sa += a; sa2 += a * a; sx += xv; sx2 += xv * xv; sax += a * xv;
  }
  __shared__ float red[5 * 128];
  if (h == 1) {
    red[c] = sa; red[128 + c] = sa2; red[256 + c] = sx; red[384 + c] = sx2; red[512 + c] = sax;
  }
  __syncthreads();
  if (h == 0) {
    float* p = partial + (size_t)b * 640;
    p[c] = sa + red[c];
    p[128 + c] = sa2 + red[128 + c];
    p[256 + c] = sx + red[256 + c];
    p[384 + c] = sx2 + red[384 + c];
    p[512 + c] = sax + red[512 + c];
  }
}

// ---------------- fold both BNs into x' = relu(A*agg + B*x + C) ----------------
__global__ void bn_coeffs(const float* __restrict__ partial, const float* __restrict__ bn1g,
                          const float* __restrict__ bn1b, const float* __restrict__ bn2g,
                          const float* __restrict__ bn2b, float* __restrict__ abc, int l) {
  int c = threadIdx.x;
  float sa = 0, sa2 = 0, sx = 0, sx2 = 0, sax = 0;
  for (int b = 0; b < 200; b++) {
    const float* p = partial + (size_t)b * 640;
    sa += p[c]; sa2 += p[128 + c]; sx += p[256 + c]; sx2 += p[384 + c]; sax += p[512 + c];
  }
  const double Ninv = 1.0 / (double)NN;
  double Ea = sa * Ninv, Ea2 = sa2 * Ninv, Ex = sx * Ninv, Ex2 = sx2 * Ninv, Eax = sax * Ninv;
  double var1 = Ea2 - Ea * Ea;
  double g1 = bn1g[l * 128 + c], b1 = bn1b[l * 128 + c];
  double g2 = bn2g[l * 128 + c], b2v = bn2b[l * 128 + c];
  double s1 = g1 / sqrt(var1 + 1e-5);
  double t1 = b1 - Ea * s1;
  double mu_o = s1 * Ea + t1 + Ex;
  double Eo2 = s1 * s1 * Ea2 + 2.0 * s1 * t1 * Ea + t1 * t1 + 2.0 * (s1 * Eax + t1 * Ex) + Ex2;
  double var_o = Eo2 - mu_o * mu_o;
  double s2 = g2 / sqrt(var_o + 1e-5);
  double t2 = b2v - mu_o * s2;
  abc[c] = (float)(s1 * s2);
  abc[128 + c] = (float)s2;
  abc[256 + c] = (float)(t1 * s2 + t2);
}

// ---------------- x = relu(A*agg + B*x + C), also emit bf16 ----------------
__global__ void fuse_bn(const float* __restrict__ agg, float* __restrict__ x,
                        unsigned short* __restrict__ xh, const float* __restrict__ abc) {
  const int total = NN * 32;
  for (int idx = blockIdx.x * 256 + threadIdx.x; idx < total; idx += gridDim.x * 256) {
    int c4 = (idx & 31) * 4;
    size_t base = (size_t)idx * 4;
    float4 a = *(const float4*)(agg + base);
    float4 xv = *(const float4*)(x + base);
    float4 A = *(const float4*)(abc + c4);
    float4 B = *(const float4*)(abc + 128 + c4);
    float4 C = *(const float4*)(abc + 256 + c4);
    float4 o;
    o.x = fmaxf(fmaf(A.x, a.x, fmaf(B.x, xv.x, C.x)), 0.f);
    o.y = fmaxf(fmaf(A.y, a.y, fmaf(B.y, xv.y, C.y)), 0.f);
    o.z = fmaxf(fmaf(A.z, a.z, fmaf(B.z, xv.z, C.z)), 0.f);
    o.w = fmaxf(fmaf(A.w, a.w, fmaf(B.w, xv.w, C.w)), 0.f);
    *(float4*)(x + base) = o;
    ushort4 hh;
    hh.x = f2bf(o.x); hh.y = f2bf(o.y); hh.z = f2bf(o.z); hh.w = f2bf(o.w);
    *(ushort4*)(xh + base) = hh;
  }
}

// ---------------- global mean pool ----------------
__global__ void pool_mean(const float* __restrict__ x, float* __restrict__ gp) {
  int g = blockIdx.x, c = threadIdx.x;  // 128 threads
  float s = 0.f;
  const float* base = x + (size_t)g * NPG * EMBD + c;
  for (int r = 0; r < NPG; r++) s += base[(size_t)r * EMBD];
  gp[g * EMBD + c] = s * (1.f / NPG);
}

// ---------------- final MLP ----------------
__global__ void mlp_out(const float* __restrict__ gp, const float* __restrict__ W1,
                        const float* __restrict__ b1, const float* __restrict__ W2,
                        const float* __restrict__ b2, float* __restrict__ out) {
  int g = blockIdx.x, c = threadIdx.x;  // 128 threads
  __shared__ float gl[128];
  __shared__ float red[128];
  gl[c] = gp[g * EMBD + c];
  __syncthreads();
  float acc = b1[c];
  for (int k = 0; k < 128; k++) acc = fmaf(gl[k], W1[k * EMBD + c], acc);
  red[c] = fmaxf(acc, 0.f) * W2[c];
  __syncthreads();
  for (int s = 64; s > 0; s >>= 1) {
    if (c < s) red[c] += red[c + s];
    __syncthreads();
  }
  if (c == 0) out[g] = red[0] + b2[0];
}

extern "C" void kernel_launch(void* const* d_in, const int* in_sizes, int n_in,
                              void* d_out, int out_size, void* d_ws, size_t ws_size,
                              hipStream_t stream) {
  const float* pos = (const float*)d_in[0];
  const float* emb = (const float*)d_in[1];
  const float* Wf = (const float*)d_in[2];
  const float* bf = (const float*)d_in[3];
  const float* Ws = (const float*)d_in[4];
  const float* bs = (const float*)d_in[5];
  const float* bn1g = (const float*)d_in[6];
  const float* bn1b = (const float*)d_in[7];
  const float* bn2g = (const float*)d_in[8];
  const float* bn2b = (const float*)d_in[9];
  const float* W1 = (const float*)d_in[10];
  const float* b1 = (const float*)d_in[11];
  const float* W2 = (const float*)d_in[12];
  const float* b2 = (const float*)d_in[13];
  const int* z = (const int*)d_in[14];
  const int* ei = (const int*)d_in[16];
  float* out = (float*)d_out;

  char* ws = (char*)d_ws;
  float* x = (float*)(ws + 0);                       // 25,600,000 B
  unsigned short* xh = (unsigned short*)(ws + 25600000);   // 12,800,000
  unsigned short* P = (unsigned short*)(ws + 38400000);    // 51,200,000
  float* agg = (float*)(ws + 89600000);              // 25,600,000
  float* dist = (float*)(ws + 115200000);            // 3,200,000
  unsigned short* whT = (unsigned short*)(ws + 118400000); // 524,288
  float* partial = (float*)(ws + 118924288);         // 512,000
  float* abc = (float*)(ws + 119436288);             // 1,536
  float* gp = (float*)(ws + 119437824);              // 51,200

  prep_w<<<1024, 256, 0, stream>>>(Wf, Ws, whT);
  gather_x<<<2048, 256, 0, stream>>>(emb, z, x, xh);
  edge_dist<<<2048, 256, 0, stream>>>(pos, ei, dist);
  for (int l = 0; l < NL; l++) {
    gemm_proj<<<dim3(391, 8), 256, 0, stream>>>(xh, whT, P, l);
    edge_pass<<<400, 512, 0, stream>>>(P, dist, ei, Wf, bf, Ws, bs, agg, l);
    col_stats<<<200, 256, 0, stream>>>(agg, x, partial);
    bn_coeffs<<<1, 128, 0, stream>>>(partial, bn1g, bn1b, bn2g, bn2b, abc, l);
    fuse_bn<<<2048, 256, 0, stream>>>(agg, x, xh, abc);
  }
  pool_mean<<<100, 128, 0, stream>>>(x, gp);
  mlp_out<<<100, 128, 0, stream>>>(gp, W1, b1, W2, b2, out);
}

// Round 2
// 925.627 us; speedup vs baseline: 3.4403x; 3.4403x over previous
//
#include <hip/hip_runtime.h>

#define NN 50000
#define NG 100
#define NPG 500
#define NE 800000
#define EPG 8000
#define EMBD 128
#define NL 4

typedef __attribute__((ext_vector_type(8))) short short8v;
typedef __attribute__((ext_vector_type(4))) float float4v;

__device__ __forceinline__ unsigned short f2bf(float v) {
  unsigned u = __float_as_uint(v);
  u += 0x7FFFu + ((u >> 16) & 1u);
  return (unsigned short)(u >> 16);
}
__device__ __forceinline__ float bf2f(unsigned short h) {
  return __uint_as_float(((unsigned)h) << 16);
}

// ---------------- Wcat^T (bf16) prep: whT[l][cc][k], cc = m*128+c ----------------
__global__ void prep_w(const float* __restrict__ Wf, const float* __restrict__ Ws,
                       unsigned short* __restrict__ whT) {
  int idx = blockIdx.x * 256 + threadIdx.x;   // 4*512*128 = 262144
  int k = idx & 127;
  int cc = (idx >> 7) & 511;
  int l = idx >> 16;
  int m = cc >> 7, c = cc & 127;
  const float* W = (m < 2) ? Wf : Ws;
  int row = ((m & 1) << 7) + k;
  whT[idx] = f2bf(W[(size_t)l * 32896 + (size_t)row * 128 + c]);
}

// ---------------- x0 = emb[z] ----------------
__global__ void gather_x(const float* __restrict__ emb, const int* __restrict__ z,
                         float* __restrict__ x, unsigned short* __restrict__ xh) {
  const int total = NN * 32;
  for (int idx = blockIdx.x * 256 + threadIdx.x; idx < total; idx += gridDim.x * 256) {
    int n = idx >> 5, c4 = (idx & 31) * 4;
    float4 v = *(const float4*)(emb + (size_t)z[n] * EMBD + c4);
    size_t base = (size_t)idx * 4;
    *(float4*)(x + base) = v;
    ushort4 h;
    h.x = f2bf(v.x); h.y = f2bf(v.y); h.z = f2bf(v.z); h.w = f2bf(v.w);
    *(ushort4*)(xh + base) = h;
  }
}

// ---------------- CSR build: deg count ----------------
__global__ void deg_count(const int* __restrict__ ei, int* __restrict__ deg) {
  for (int e = blockIdx.x * 256 + threadIdx.x; e < NE; e += gridDim.x * 256)
    atomicAdd(&deg[ei[NE + e]], 1);
}

// ---------------- CSR build: per-graph exclusive prefix ----------------
__global__ void csr_prefix(const int* __restrict__ deg, int* __restrict__ offs,
                           int* __restrict__ cursor) {
  __shared__ int s[512];
  int g = blockIdx.x, t = threadIdx.x;
  int v = (t < NPG) ? deg[g * NPG + t] : 0;
  s[t] = v;
  __syncthreads();
  for (int d = 1; d < 512; d <<= 1) {
    int a = (t >= d) ? s[t - d] : 0;
    __syncthreads();
    s[t] += a;
    __syncthreads();
  }
  if (t < NPG) {
    int o = g * EPG + s[t] - v;
    offs[g * NPG + t] = o;
    cursor[g * NPG + t] = o;
  }
}

// ---------------- CSR build: scatter (j, dist) ----------------
__global__ void csr_scatter(const int* __restrict__ ei, const float* __restrict__ pos,
                            int* __restrict__ cursor, uint2* __restrict__ csr) {
  for (int e = blockIdx.x * 256 + threadIdx.x; e < NE; e += gridDim.x * 256) {
    int j = ei[e], i = ei[NE + e];
    float dx = pos[i * 3 + 0] - pos[j * 3 + 0];
    float dy = pos[i * 3 + 1] - pos[j * 3 + 1];
    float dz = pos[i * 3 + 2] - pos[j * 3 + 2];
    float dist = sqrtf(dx * dx + dy * dy + dz * dz);
    int p = atomicAdd(&cursor[i], 1);
    csr[p] = make_uint2((unsigned)j, __float_as_uint(dist));
  }
}

// ---------------- P[n][512] = x(bf16) @ Wcat (MFMA 16x16x32 bf16) ----------------
#define BM 128
#define BN 64
__global__ __launch_bounds__(256, 3) void gemm_proj(const unsigned short* __restrict__ xh,
                                                    const unsigned short* __restrict__ whT,
                                                    unsigned short* __restrict__ P, int l) {
  __shared__ __align__(16) unsigned short sA[BM * 128];
  __shared__ __align__(16) unsigned short sB[BN * 128];
  const int tid = threadIdx.x;
  const int R0 = blockIdx.x * BM;
  const int C0 = blockIdx.y * BN;
  for (int gid = tid; gid < BM * 16; gid += 256) {
    int row = gid >> 4, gc = gid & 15;
    int grow = R0 + row;
    uint4 v = make_uint4(0u, 0u, 0u, 0u);
    if (grow < NN) v = *(const uint4*)(xh + (size_t)grow * 128 + gc * 8);
    int gs = (gc & 8) | ((gc ^ row) & 7);
    *(uint4*)((char*)sA + row * 256 + gs * 16) = v;
  }
  for (int gid = tid; gid < BN * 16; gid += 256) {
    int c = gid >> 4, gc = gid & 15;
    uint4 v = *(const uint4*)(whT + ((size_t)l * 512 + C0 + c) * 128 + gc * 8);
    int gs = (gc & 8) | ((gc ^ c) & 7);
    *(uint4*)((char*)sB + c * 256 + gs * 16) = v;
  }
  __syncthreads();
  const int w = tid >> 6, lane = tid & 63;
  const int lr = lane & 15, lk = lane >> 4;
  float4v acc[2][4];
#pragma unroll
  for (int i = 0; i < 2; i++)
#pragma unroll
    for (int j = 0; j < 4; j++) acc[i][j] = (float4v){0.f, 0.f, 0.f, 0.f};
#pragma unroll
  for (int kb = 0; kb < 4; kb++) {
    int g = kb * 4 + lk;
    short8v a[2], b[4];
#pragma unroll
    for (int rf = 0; rf < 2; rf++) {
      int row = w * 32 + rf * 16 + lr;
      int gs = (g & 8) | ((g ^ row) & 7);
      a[rf] = *(const short8v*)((const char*)sA + row * 256 + gs * 16);
    }
#pragma unroll
    for (int cf = 0; cf < 4; cf++) {
      int c = cf * 16 + lr;
      int gs = (g & 8) | ((g ^ c) & 7);
      b[cf] = *(const short8v*)((const char*)sB + c * 256 + gs * 16);
    }
#pragma unroll
    for (int rf = 0; rf < 2; rf++)
#pragma unroll
      for (int cf = 0; cf < 4; cf++)
        acc[rf][cf] = __builtin_amdgcn_mfma_f32_16x16x32_bf16(a[rf], b[cf], acc[rf][cf], 0, 0, 0);
  }
#pragma unroll
  for (int rf = 0; rf < 2; rf++) {
#pragma unroll
    for (int cf = 0; cf < 4; cf++) {
      int col = C0 + cf * 16 + lr;
#pragma unroll
      for (int j = 0; j < 4; j++) {
        int row = R0 + w * 32 + rf * 16 + lk * 4 + j;
        if (row < NN) P[(size_t)row * 512 + col] = f2bf(acc[rf][cf][j]);
      }
    }
  }
}

// ---------------- edge gather: one wave per dst node, 2 features per lane ----------------
__global__ __launch_bounds__(256) void edge_gather(const unsigned short* __restrict__ P,
                                                   const uint2* __restrict__ csr,
                                                   const int* __restrict__ offs,
                                                   const int* __restrict__ deg,
                                                   const float* __restrict__ Wf,
                                                   const float* __restrict__ bf,
                                                   const float* __restrict__ Ws,
                                                   const float* __restrict__ bs,
                                                   float* __restrict__ agg, int l) {
  const int lane = threadIdx.x & 63;
  const int wid = __builtin_amdgcn_readfirstlane(threadIdx.x >> 6);
  const int i = blockIdx.x * 4 + wid;  // dst node (grid = 12500 exactly covers 50000)
  const int f0 = lane * 2;

  const uint* Piu = (const uint*)(P + (size_t)i * 512);
  uint pif = Piu[lane];        // x_i part, features f0,f0+1 (cols 0..127)
  uint pis = Piu[128 + lane];  // x_i part of s-proj (cols 256..383)

  float2 wfd = *(const float2*)(Wf + (size_t)l * 32896 + 256 * 128 + f0);
  float2 wsd = *(const float2*)(Ws + (size_t)l * 32896 + 256 * 128 + f0);
  float2 bfv = *(const float2*)(bf + l * 128 + f0);
  float2 bsv = *(const float2*)(bs + l * 128 + f0);

  float basef0 = __uint_as_float(pif << 16) + bfv.x;
  float basef1 = __uint_as_float(pif & 0xffff0000u) + bfv.y;
  float bases0 = __uint_as_float(pis << 16) + bsv.x;
  float bases1 = __uint_as_float(pis & 0xffff0000u) + bsv.y;

  const int off = offs[i];
  const int nd = deg[i];
  float acc0 = 0.f, acc1 = 0.f;
  for (int k = 0; k < nd; k++) {
    uint2 ed = csr[off + k];
    int j = (int)ed.x;
    float dv = __uint_as_float(ed.y);
    const uint* Pju = (const uint*)(P + (size_t)j * 512);
    uint vf = Pju[64 + lane];   // x_j part of f-proj (cols 128..255)
    uint vs = Pju[192 + lane];  // x_j part of s-proj (cols 384..511)
    float jf0 = __uint_as_float(vf << 16);
    float jf1 = __uint_as_float(vf & 0xffff0000u);
    float js0 = __uint_as_float(vs << 16);
    float js1 = __uint_as_float(vs & 0xffff0000u);
    float pf0 = fmaf(dv, wfd.x, basef0 + jf0);
    float pf1 = fmaf(dv, wfd.y, basef1 + jf1);
    float ps0 = fmaf(dv, wsd.x, bases0 + js0);
    float ps1 = fmaf(dv, wsd.y, bases1 + js1);
    float sg0 = 1.f / (1.f + __expf(-pf0));
    float sg1 = 1.f / (1.f + __expf(-pf1));
    float sp0 = fmaxf(ps0, 0.f) + __logf(1.f + __expf(-fabsf(ps0)));
    float sp1 = fmaxf(ps1, 0.f) + __logf(1.f + __expf(-fabsf(ps1)));
    acc0 = fmaf(sg0, sp0, acc0);
    acc1 = fmaf(sg1, sp1, acc1);
  }
  float2 o = make_float2(acc0, acc1);
  *(float2*)(agg + (size_t)i * EMBD + f0) = o;
}

// ---------------- per-column partial sums for both BNs ----------------
__global__ void col_stats(const float* __restrict__ agg, const float* __restrict__ x,
                          float* __restrict__ partial) {
  const int b = blockIdx.x, tid = threadIdx.x;
  const int c = tid & 127, h = tid >> 7;
  float sa = 0, sa2 = 0, sx = 0, sx2 = 0, sax = 0;
  int r0 = b * 250;
  for (int rr = h; rr < 250; rr += 2) {
    size_t idx = (size_t)(r0 + rr) * EMBD + c;
    float a = agg[idx], xv = x[idx];
    sa += a; sa2 += a * a; sx += xv; sx2 += xv * xv; sax += a * xv;
  }
  __shared__ float red[5 * 128];
  if (h == 1) {
    red[c] = sa; red[128 + c] = sa2; red[256 + c] = sx; red[384 + c] = sx2; red[512 + c] = sax;
  }
  __syncthreads();
  if (h == 0) {
    float* p = partial + (size_t)b * 640;
    p[c] = sa + red[c];
    p[128 + c] = sa2 + red[128 + c];
    p[256 + c] = sx + red[256 + c];
    p[384 + c] = sx2 + red[384 + c];
    p[512 + c] = sax + red[512 + c];
  }
}

// ---------------- fold both BNs into x' = relu(A*agg + B*x + C) ----------------
__global__ void bn_coeffs(const float* __restrict__ partial, const float* __restrict__ bn1g,
                          const float* __restrict__ bn1b, const float* __restrict__ bn2g,
                          const float* __restrict__ bn2b, float* __restrict__ abc, int l) {
  int c = threadIdx.x;
  float sa = 0, sa2 = 0, sx = 0, sx2 = 0, sax = 0;
  for (int b = 0; b < 200; b++) {
    const float* p = partial + (size_t)b * 640;
    sa += p[c]; sa2 += p[128 + c]; sx += p[256 + c]; sx2 += p[384 + c]; sax += p[512 + c];
  }
  const double Ninv = 1.0 / (double)NN;
  double Ea = sa * Ninv, Ea2 = sa2 * Ninv, Ex = sx * Ninv, Ex2 = sx2 * Ninv, Eax = sax * Ninv;
  double var1 = Ea2 - Ea * Ea;
  double g1 = bn1g[l * 128 + c], b1 = bn1b[l * 128 + c];
  double g2 = bn2g[l * 128 + c], b2v = bn2b[l * 128 + c];
  double s1 = g1 / sqrt(var1 + 1e-5);
  double t1 = b1 - Ea * s1;
  double mu_o = s1 * Ea + t1 + Ex;
  double Eo2 = s1 * s1 * Ea2 + 2.0 * s1 * t1 * Ea + t1 * t1 + 2.0 * (s1 * Eax + t1 * Ex) + Ex2;
  double var_o = Eo2 - mu_o * mu_o;
  double s2 = g2 / sqrt(var_o + 1e-5);
  double t2 = b2v - mu_o * s2;
  abc[c] = (float)(s1 * s2);
  abc[128 + c] = (float)s2;
  abc[256 + c] = (float)(t1 * s2 + t2);
}

// ---------------- x = relu(A*agg + B*x + C), also emit bf16 ----------------
__global__ void fuse_bn(const float* __restrict__ agg, float* __restrict__ x,
                        unsigned short* __restrict__ xh, const float* __restrict__ abc) {
  const int total = NN * 32;
  for (int idx = blockIdx.x * 256 + threadIdx.x; idx < total; idx += gridDim.x * 256) {
    int c4 = (idx & 31) * 4;
    size_t base = (size_t)idx * 4;
    float4 a = *(const float4*)(agg + base);
    float4 xv = *(const float4*)(x + base);
    float4 A = *(const float4*)(abc + c4);
    float4 B = *(const float4*)(abc + 128 + c4);
    float4 C = *(const float4*)(abc + 256 + c4);
    float4 o;
    o.x = fmaxf(fmaf(A.x, a.x, fmaf(B.x, xv.x, C.x)), 0.f);
    o.y = fmaxf(fmaf(A.y, a.y, fmaf(B.y, xv.y, C.y)), 0.f);
    o.z = fmaxf(fmaf(A.z, a.z, fmaf(B.z, xv.z, C.z)), 0.f);
    o.w = fmaxf(fmaf(A.w, a.w, fmaf(B.w, xv.w, C.w)), 0.f);
    *(float4*)(x + base) = o;
    ushort4 hh;
    hh.x = f2bf(o.x); hh.y = f2bf(o.y); hh.z = f2bf(o.z); hh.w = f2bf(o.w);
    *(ushort4*)(xh + base) = hh;
  }
}

// ---------------- global mean pool ----------------
__global__ void pool_mean(const float* __restrict__ x, float* __restrict__ gp) {
  int g = blockIdx.x, c = threadIdx.x;
  float s = 0.f;
  const float* base = x + (size_t)g * NPG * EMBD + c;
  for (int r = 0; r < NPG; r++) s += base[(size_t)r * EMBD];
  gp[g * EMBD + c] = s * (1.f / NPG);
}

// ---------------- final MLP ----------------
__global__ void mlp_out(const float* __restrict__ gp, const float* __restrict__ W1,
                        const float* __restrict__ b1, const float* __restrict__ W2,
                        const float* __restrict__ b2, float* __restrict__ out) {
  int g = blockIdx.x, c = threadIdx.x;
  __shared__ float gl[128];
  __shared__ float red[128];
  gl[c] = gp[g * EMBD + c];
  __syncthreads();
  float acc = b1[c];
  for (int k = 0; k < 128; k++) acc = fmaf(gl[k], W1[k * EMBD + c], acc);
  red[c] = fmaxf(acc, 0.f) * W2[c];
  __syncthreads();
  for (int s = 64; s > 0; s >>= 1) {
    if (c < s) red[c] += red[c + s];
    __syncthreads();
  }
  if (c == 0) out[g] = red[0] + b2[0];
}

extern "C" void kernel_launch(void* const* d_in, const int* in_sizes, int n_in,
                              void* d_out, int out_size, void* d_ws, size_t ws_size,
                              hipStream_t stream) {
  const float* pos = (const float*)d_in[0];
  const float* emb = (const float*)d_in[1];
  const float* Wf = (const float*)d_in[2];
  const float* bf = (const float*)d_in[3];
  const float* Ws = (const float*)d_in[4];
  const float* bs = (const float*)d_in[5];
  const float* bn1g = (const float*)d_in[6];
  const float* bn1b = (const float*)d_in[7];
  const float* bn2g = (const float*)d_in[8];
  const float* bn2b = (const float*)d_in[9];
  const float* W1 = (const float*)d_in[10];
  const float* b1 = (const float*)d_in[11];
  const float* W2 = (const float*)d_in[12];
  const float* b2 = (const float*)d_in[13];
  const int* z = (const int*)d_in[14];
  const int* ei = (const int*)d_in[16];
  float* out = (float*)d_out;

  char* ws = (char*)d_ws;
  float* x = (float*)(ws + 0);                               // 25,600,000
  unsigned short* xh = (unsigned short*)(ws + 25600000);     // 12,800,000
  unsigned short* P = (unsigned short*)(ws + 38400000);      // 51,200,000
  float* agg = (float*)(ws + 89600000);                      // 25,600,000
  uint2* csr = (uint2*)(ws + 115200000);                     //  6,400,000
  int* deg = (int*)(ws + 121600000);                         //    200,000
  int* offs = (int*)(ws + 121800000);                        //    200,000
  int* cursor = (int*)(ws + 122000000);                      //    200,000
  unsigned short* whT = (unsigned short*)(ws + 122200000);   //    524,288
  float* partial = (float*)(ws + 122724288);                 //    512,000
  float* abc = (float*)(ws + 123236288);                     //      1,536
  float* gp = (float*)(ws + 123237824);                      //     51,200

  hipMemsetAsync((void*)deg, 0, 600000, stream);  // deg + offs + cursor
  prep_w<<<1024, 256, 0, stream>>>(Wf, Ws, whT);
  gather_x<<<2048, 256, 0, stream>>>(emb, z, x, xh);
  deg_count<<<2048, 256, 0, stream>>>(ei, deg);
  csr_prefix<<<NG, 512, 0, stream>>>(deg, offs, cursor);
  csr_scatter<<<2048, 256, 0, stream>>>(ei, pos, cursor, csr);
  for (int l = 0; l < NL; l++) {
    gemm_proj<<<dim3(391, 8), 256, 0, stream>>>(xh, whT, P, l);
    edge_gather<<<NN / 4, 256, 0, stream>>>(P, csr, offs, deg, Wf, bf, Ws, bs, agg, l);
    col_stats<<<200, 256, 0, stream>>>(agg, x, partial);
    bn_coeffs<<<1, 128, 0, stream>>>(partial, bn1g, bn1b, bn2g, bn2b, abc, l);
    fuse_bn<<<2048, 256, 0, stream>>>(agg, x, xh, abc);
  }
  pool_mean<<<100, 128, 0, stream>>>(x, gp);
  mlp_out<<<100, 128, 0, stream>>>(gp, W1, b1, W2, b2, out);
}

// Round 3
// 688.979 us; speedup vs baseline: 4.6219x; 1.3435x over previous
//
#include <hip/hip_runtime.h>

#define NN 50000
#define NG 100
#define NPG 500
#define NE 800000
#define EPG 8000
#define EMBD 128
#define NL 4

typedef __attribute__((ext_vector_type(8))) short short8v;
typedef __attribute__((ext_vector_type(4))) float float4v;
typedef __attribute__((ext_vector_type(2))) float f2;

__device__ __forceinline__ unsigned short f2bf(float v) {
  unsigned u = __float_as_uint(v);
  u += 0x7FFFu + ((u >> 16) & 1u);
  return (unsigned short)(u >> 16);
}
__device__ __forceinline__ float bf2f(unsigned short h) {
  return __uint_as_float(((unsigned)h) << 16);
}

__device__ __forceinline__ float fexp2(float x) {
#if __has_builtin(__builtin_amdgcn_exp2f)
  return __builtin_amdgcn_exp2f(x);
#else
  float r; asm("v_exp_f32 %0, %1" : "=v"(r) : "v"(x)); return r;
#endif
}
__device__ __forceinline__ float flog2(float x) {
#if __has_builtin(__builtin_amdgcn_logf)
  return __builtin_amdgcn_logf(x);
#else
  float r; asm("v_log_f32 %0, %1" : "=v"(r) : "v"(x)); return r;
#endif
}
__device__ __forceinline__ float frcp(float x) {
#if __has_builtin(__builtin_amdgcn_rcpf)
  return __builtin_amdgcn_rcpf(x);
#else
  float r; asm("v_rcp_f32 %0, %1" : "=v"(r) : "v"(x)); return r;
#endif
}

__device__ __forceinline__ f2 unpk(unsigned v) {
  f2 r;
  r.x = __uint_as_float(v << 16);
  r.y = __uint_as_float(v & 0xffff0000u);
  return r;
}

// ---------------- Wcat^T (bf16) prep: whT[l][cc][k], cc = m*128+c ----------------
__global__ void prep_w(const float* __restrict__ Wf, const float* __restrict__ Ws,
                       unsigned short* __restrict__ whT) {
  int idx = blockIdx.x * 256 + threadIdx.x;   // 4*512*128 = 262144
  int k = idx & 127;
  int cc = (idx >> 7) & 511;
  int l = idx >> 16;
  int m = cc >> 7, c = cc & 127;
  const float* W = (m < 2) ? Wf : Ws;
  int row = ((m & 1) << 7) + k;
  whT[idx] = f2bf(W[(size_t)l * 32896 + (size_t)row * 128 + c]);
}

// ---------------- x0 = emb[z] ----------------
__global__ void gather_x(const float* __restrict__ emb, const int* __restrict__ z,
                         float* __restrict__ x, unsigned short* __restrict__ xh) {
  const int total = NN * 32;
  for (int idx = blockIdx.x * 256 + threadIdx.x; idx < total; idx += gridDim.x * 256) {
    int n = idx >> 5, c4 = (idx & 31) * 4;
    float4 v = *(const float4*)(emb + (size_t)z[n] * EMBD + c4);
    size_t base = (size_t)idx * 4;
    *(float4*)(x + base) = v;
    ushort4 h;
    h.x = f2bf(v.x); h.y = f2bf(v.y); h.z = f2bf(v.z); h.w = f2bf(v.w);
    *(ushort4*)(xh + base) = h;
  }
}

// ---------------- CSR build: one block per graph, all in LDS ----------------
__global__ __launch_bounds__(512) void csr_build(const int* __restrict__ ei,
                                                 const float* __restrict__ pos,
                                                 int* __restrict__ offs, int* __restrict__ deg,
                                                 uint2* __restrict__ csr) {
  __shared__ int hist[NPG];
  __shared__ int scan[512];
  const int g = blockIdx.x, t = threadIdx.x;
  const int nbase = g * NPG;
  const int e0 = g * EPG;
  for (int n = t; n < NPG; n += 512) hist[n] = 0;
  __syncthreads();
  for (int e = t; e < EPG; e += 512) atomicAdd(&hist[ei[NE + e0 + e] - nbase], 1);
  __syncthreads();
  int v = (t < NPG) ? hist[t] : 0;
  scan[t] = v;
  __syncthreads();
  for (int d = 1; d < 512; d <<= 1) {
    int a = (t >= d) ? scan[t - d] : 0;
    __syncthreads();
    scan[t] += a;
    __syncthreads();
  }
  if (t < NPG) {
    int off = scan[t] - v;           // exclusive, within graph
    offs[nbase + t] = e0 + off;
    deg[nbase + t] = v;
    hist[t] = off;                   // reuse as cursor
  }
  __syncthreads();
  for (int e = t; e < EPG; e += 512) {
    int j = ei[e0 + e];
    int i = ei[NE + e0 + e];
    float dx = pos[i * 3 + 0] - pos[j * 3 + 0];
    float dy = pos[i * 3 + 1] - pos[j * 3 + 1];
    float dz = pos[i * 3 + 2] - pos[j * 3 + 2];
    float dist = sqrtf(dx * dx + dy * dy + dz * dz);
    int p = atomicAdd(&hist[i - nbase], 1);
    csr[e0 + p] = make_uint2((unsigned)j, __float_as_uint(dist));
  }
}

// ---------------- P[n][512] = x(bf16) @ Wcat (MFMA 16x16x32 bf16) ----------------
#define BM 128
#define BN 64
__global__ __launch_bounds__(256, 3) void gemm_proj(const unsigned short* __restrict__ xh,
                                                    const unsigned short* __restrict__ whT,
                                                    unsigned short* __restrict__ P, int l) {
  __shared__ __align__(16) unsigned short sA[BM * 128];
  __shared__ __align__(16) unsigned short sB[BN * 128];
  const int tid = threadIdx.x;
  const int R0 = blockIdx.x * BM;
  const int C0 = blockIdx.y * BN;
  for (int gid = tid; gid < BM * 16; gid += 256) {
    int row = gid >> 4, gc = gid & 15;
    int grow = R0 + row;
    uint4 v = make_uint4(0u, 0u, 0u, 0u);
    if (grow < NN) v = *(const uint4*)(xh + (size_t)grow * 128 + gc * 8);
    int gs = (gc & 8) | ((gc ^ row) & 7);
    *(uint4*)((char*)sA + row * 256 + gs * 16) = v;
  }
  for (int gid = tid; gid < BN * 16; gid += 256) {
    int c = gid >> 4, gc = gid & 15;
    uint4 v = *(const uint4*)(whT + ((size_t)l * 512 + C0 + c) * 128 + gc * 8);
    int gs = (gc & 8) | ((gc ^ c) & 7);
    *(uint4*)((char*)sB + c * 256 + gs * 16) = v;
  }
  __syncthreads();
  const int w = tid >> 6, lane = tid & 63;
  const int lr = lane & 15, lk = lane >> 4;
  float4v acc[2][4];
#pragma unroll
  for (int i = 0; i < 2; i++)
#pragma unroll
    for (int j = 0; j < 4; j++) acc[i][j] = (float4v){0.f, 0.f, 0.f, 0.f};
#pragma unroll
  for (int kb = 0; kb < 4; kb++) {
    int g = kb * 4 + lk;
    short8v a[2], b[4];
#pragma unroll
    for (int rf = 0; rf < 2; rf++) {
      int row = w * 32 + rf * 16 + lr;
      int gs = (g & 8) | ((g ^ row) & 7);
      a[rf] = *(const short8v*)((const char*)sA + row * 256 + gs * 16);
    }
#pragma unroll
    for (int cf = 0; cf < 4; cf++) {
      int c = cf * 16 + lr;
      int gs = (g & 8) | ((g ^ c) & 7);
      b[cf] = *(const short8v*)((const char*)sB + c * 256 + gs * 16);
    }
#pragma unroll
    for (int rf = 0; rf < 2; rf++)
#pragma unroll
      for (int cf = 0; cf < 4; cf++)
        acc[rf][cf] = __builtin_amdgcn_mfma_f32_16x16x32_bf16(a[rf], b[cf], acc[rf][cf], 0, 0, 0);
  }
#pragma unroll
  for (int rf = 0; rf < 2; rf++) {
#pragma unroll
    for (int cf = 0; cf < 4; cf++) {
      int col = C0 + cf * 16 + lr;
#pragma unroll
      for (int j = 0; j < 4; j++) {
        int row = R0 + w * 32 + rf * 16 + lk * 4 + j;
        if (row < NN) P[(size_t)row * 512 + col] = f2bf(acc[rf][cf][j]);
      }
    }
  }
}

// ---------------- edge gather: one wave per dst node, exp2-domain math ----------------
__global__ __launch_bounds__(256) void edge_gather(const unsigned short* __restrict__ P,
                                                   const uint2* __restrict__ csr,
                                                   const int* __restrict__ offs,
                                                   const int* __restrict__ deg,
                                                   const float* __restrict__ Wf,
                                                   const float* __restrict__ bf,
                                                   const float* __restrict__ Ws,
                                                   const float* __restrict__ bs,
                                                   float* __restrict__ agg, int l) {
  const float L = 1.4426950408889634f;   // log2(e)
  const float LN2 = 0.6931471805599453f;
  const int lane = threadIdx.x & 63;
  const int wid = __builtin_amdgcn_readfirstlane(threadIdx.x >> 6);
  const int i = blockIdx.x * 4 + wid;    // dst node; grid = 12500 covers 50000 exactly
  const int f0 = lane * 2;

  const unsigned* Piu = (const unsigned*)(P + (size_t)i * 512);
  unsigned pif = Piu[lane];        // x_i f-part (cols 0..127)
  unsigned pis = Piu[128 + lane];  // x_i s-part (cols 256..383)

  float2 wfd = *(const float2*)(Wf + (size_t)l * 32896 + 256 * 128 + f0);
  float2 wsd = *(const float2*)(Ws + (size_t)l * 32896 + 256 * 128 + f0);
  float2 bfv = *(const float2*)(bf + l * 128 + f0);
  float2 bsv = *(const float2*)(bs + l * 128 + f0);

  // pre-scaled by L: pf*L = jf*L + (base + dv*wfd)*L
  f2 bflv, bslv, wflv, wslv;
  {
    f2 pi_f = unpk(pif), pi_s = unpk(pis);
    bflv.x = (pi_f.x + bfv.x) * L; bflv.y = (pi_f.y + bfv.y) * L;
    bslv.x = (pi_s.x + bsv.x) * L; bslv.y = (pi_s.y + bsv.y) * L;
    wflv.x = wfd.x * L; wflv.y = wfd.y * L;
    wslv.x = wsd.x * L; wslv.y = wsd.y * L;
  }

  const int off = __builtin_amdgcn_readfirstlane(offs[i]);
  const int nd = __builtin_amdgcn_readfirstlane(deg[i]);
  const uint2* ep = csr + off;
  f2 acc = (f2){0.f, 0.f};

#define EDGE_BODY(DVU, VF, VS)                                     \
  {                                                                \
    float dv = __uint_as_float(DVU);                               \
    f2 cf = bflv + dv * wflv;                                      \
    f2 cs = bslv + dv * wslv;                                      \
    f2 pf = unpk(VF) * L + cf;                                     \
    f2 ps = unpk(VS) * L + cs;                                     \
    f2 a, b, r, lg;                                                \
    a.x = fexp2(-pf.x); a.y = fexp2(-pf.y);                        \
    b.x = fexp2(ps.x);  b.y = fexp2(ps.y);                         \
    r.x = frcp(a.x + 1.f); r.y = frcp(a.y + 1.f);                  \
    lg.x = flog2(b.x + 1.f); lg.y = flog2(b.y + 1.f);              \
    acc += r * lg;                                                 \
  }

  int k = 0;
  for (; k + 1 < nd; k += 2) {
    uint2 ed0 = ep[k], ed1 = ep[k + 1];
    unsigned j0 = __builtin_amdgcn_readfirstlane(ed0.x);
    unsigned j1 = __builtin_amdgcn_readfirstlane(ed1.x);
    unsigned d0 = __builtin_amdgcn_readfirstlane(ed0.y);
    unsigned d1 = __builtin_amdgcn_readfirstlane(ed1.y);
    const unsigned* B0 = (const unsigned*)(P + (size_t)j0 * 512);
    const unsigned* B1 = (const unsigned*)(P + (size_t)j1 * 512);
    unsigned vf0 = B0[64 + lane], vs0 = B0[192 + lane];
    unsigned vf1 = B1[64 + lane], vs1 = B1[192 + lane];
    EDGE_BODY(d0, vf0, vs0)
    EDGE_BODY(d1, vf1, vs1)
  }
  if (k < nd) {
    uint2 ed = ep[k];
    unsigned j0 = __builtin_amdgcn_readfirstlane(ed.x);
    unsigned d0 = __builtin_amdgcn_readfirstlane(ed.y);
    const unsigned* B0 = (const unsigned*)(P + (size_t)j0 * 512);
    unsigned vf0 = B0[64 + lane], vs0 = B0[192 + lane];
    EDGE_BODY(d0, vf0, vs0)
  }
#undef EDGE_BODY

  acc.x *= LN2; acc.y *= LN2;
  *(f2*)(agg + (size_t)i * EMBD + f0) = acc;
}

// ---------------- per-column partial sums for both BNs ----------------
__global__ void col_stats(const float* __restrict__ agg, const float* __restrict__ x,
                          float* __restrict__ partial) {
  const int b = blockIdx.x, tid = threadIdx.x;
  const int c = tid & 127, h = tid >> 7;
  float sa = 0, sa2 = 0, sx = 0, sx2 = 0, sax = 0;
  int r0 = b * 250;
  for (int rr = h; rr < 250; rr += 2) {
    size_t idx = (size_t)(r0 + rr) * EMBD + c;
    float a = agg[idx], xv = x[idx];
    sa += a; sa2 += a * a; sx += xv; sx2 += xv * xv; sax += a * xv;
  }
  __shared__ float red[5 * 128];
  if (h == 1) {
    red[c] = sa; red[128 + c] = sa2; red[256 + c] = sx; red[384 + c] = sx2; red[512 + c] = sax;
  }
  __syncthreads();
  if (h == 0) {
    float* p = partial + (size_t)b * 640;
    p[c] = sa + red[c];
    p[128 + c] = sa2 + red[128 + c];
    p[256 + c] = sx + red[256 + c];
    p[384 + c] = sx2 + red[384 + c];
    p[512 + c] = sax + red[512 + c];
  }
}

// ---------------- fold both BNs into x' = relu(A*agg + B*x + C) ----------------
__global__ void bn_coeffs(const float* __restrict__ partial, const float* __restrict__ bn1g,
                          const float* __restrict__ bn1b, const float* __restrict__ bn2g,
                          const float* __restrict__ bn2b, float* __restrict__ abc, int l) {
  int c = threadIdx.x;
  float sa = 0, sa2 = 0, sx = 0, sx2 = 0, sax = 0;
  for (int b = 0; b < 200; b++) {
    const float* p = partial + (size_t)b * 640;
    sa += p[c]; sa2 += p[128 + c]; sx += p[256 + c]; sx2 += p[384 + c]; sax += p[512 + c];
  }
  const double Ninv = 1.0 / (double)NN;
  double Ea = sa * Ninv, Ea2 = sa2 * Ninv, Ex = sx * Ninv, Ex2 = sx2 * Ninv, Eax = sax * Ninv;
  double var1 = Ea2 - Ea * Ea;
  double g1 = bn1g[l * 128 + c], b1 = bn1b[l * 128 + c];
  double g2 = bn2g[l * 128 + c], b2v = bn2b[l * 128 + c];
  double s1 = g1 / sqrt(var1 + 1e-5);
  double t1 = b1 - Ea * s1;
  double mu_o = s1 * Ea + t1 + Ex;
  double Eo2 = s1 * s1 * Ea2 + 2.0 * s1 * t1 * Ea + t1 * t1 + 2.0 * (s1 * Eax + t1 * Ex) + Ex2;
  double var_o = Eo2 - mu_o * mu_o;
  double s2 = g2 / sqrt(var_o + 1e-5);
  double t2 = b2v - mu_o * s2;
  abc[c] = (float)(s1 * s2);
  abc[128 + c] = (float)s2;
  abc[256 + c] = (float)(t1 * s2 + t2);
}

// ---------------- x = relu(A*agg + B*x + C), also emit bf16 ----------------
__global__ void fuse_bn(const float* __restrict__ agg, float* __restrict__ x,
                        unsigned short* __restrict__ xh, const float* __restrict__ abc) {
  const int total = NN * 32;
  for (int idx = blockIdx.x * 256 + threadIdx.x; idx < total; idx += gridDim.x * 256) {
    int c4 = (idx & 31) * 4;
    size_t base = (size_t)idx * 4;
    float4 a = *(const float4*)(agg + base);
    float4 xv = *(const float4*)(x + base);
    float4 A = *(const float4*)(abc + c4);
    float4 B = *(const float4*)(abc + 128 + c4);
    float4 C = *(const float4*)(abc + 256 + c4);
    float4 o;
    o.x = fmaxf(fmaf(A.x, a.x, fmaf(B.x, xv.x, C.x)), 0.f);
    o.y = fmaxf(fmaf(A.y, a.y, fmaf(B.y, xv.y, C.y)), 0.f);
    o.z = fmaxf(fmaf(A.z, a.z, fmaf(B.z, xv.z, C.z)), 0.f);
    o.w = fmaxf(fmaf(A.w, a.w, fmaf(B.w, xv.w, C.w)), 0.f);
    *(float4*)(x + base) = o;
    ushort4 hh;
    hh.x = f2bf(o.x); hh.y = f2bf(o.y); hh.z = f2bf(o.z); hh.w = f2bf(o.w);
    *(ushort4*)(xh + base) = hh;
  }
}

// ---------------- global mean pool + final MLP (merged) ----------------
__global__ __launch_bounds__(512) void pool_mlp(const float* __restrict__ x,
                                                const float* __restrict__ W1,
                                                const float* __restrict__ b1,
                                                const float* __restrict__ W2,
                                                const float* __restrict__ b2,
                                                float* __restrict__ out) {
  __shared__ float red[512];
  __shared__ float gl[128];
  const int g = blockIdx.x, t = threadIdx.x;
  const int c = t & 127, q = t >> 7;
  const float* bx = x + (size_t)g * NPG * EMBD;
  float s = 0.f;
  for (int r = q; r < NPG; r += 4) s += bx[(size_t)r * EMBD + c];
  red[t] = s;
  __syncthreads();
  if (q == 0) gl[c] = (red[c] + red[128 + c] + red[256 + c] + red[384 + c]) * (1.f / NPG);
  __syncthreads();
  float acc = 0.f;
  for (int k = q * 32; k < q * 32 + 32; k++) acc = fmaf(gl[k], W1[k * EMBD + c], acc);
  red[t] = acc;
  __syncthreads();
  if (q == 0) {
    float h = fmaxf(red[c] + red[128 + c] + red[256 + c] + red[384 + c] + b1[c], 0.f);
    red[c] = h * W2[c];
  }
  __syncthreads();
  for (int sft = 64; sft > 0; sft >>= 1) {
    if (t < sft) red[t] += red[t + sft];
    __syncthreads();
  }
  if (t == 0) out[g] = red[0] + b2[0];
}

extern "C" void kernel_launch(void* const* d_in, const int* in_sizes, int n_in,
                              void* d_out, int out_size, void* d_ws, size_t ws_size,
                              hipStream_t stream) {
  const float* pos = (const float*)d_in[0];
  const float* emb = (const float*)d_in[1];
  const float* Wf = (const float*)d_in[2];
  const float* bf = (const float*)d_in[3];
  const float* Ws = (const float*)d_in[4];
  const float* bs = (const float*)d_in[5];
  const float* bn1g = (const float*)d_in[6];
  const float* bn1b = (const float*)d_in[7];
  const float* bn2g = (const float*)d_in[8];
  const float* bn2b = (const float*)d_in[9];
  const float* W1 = (const float*)d_in[10];
  const float* b1 = (const float*)d_in[11];
  const float* W2 = (const float*)d_in[12];
  const float* b2 = (const float*)d_in[13];
  const int* z = (const int*)d_in[14];
  const int* ei = (const int*)d_in[16];
  float* out = (float*)d_out;

  char* ws = (char*)d_ws;
  float* x = (float*)(ws + 0);                               // 25,600,000
  unsigned short* xh = (unsigned short*)(ws + 25600000);     // 12,800,000
  unsigned short* P = (unsigned short*)(ws + 38400000);      // 51,200,000
  float* agg = (float*)(ws + 89600000);                      // 25,600,000
  uint2* csr = (uint2*)(ws + 115200000);                     //  6,400,000
  int* deg = (int*)(ws + 121600000);                         //    200,000
  int* offs = (int*)(ws + 121800000);                        //    200,000
  unsigned short* whT = (unsigned short*)(ws + 122000000);   //    524,288
  float* partial = (float*)(ws + 122524288);                 //    512,000
  float* abc = (float*)(ws + 123036288);                     //      1,536

  prep_w<<<1024, 256, 0, stream>>>(Wf, Ws, whT);
  gather_x<<<2048, 256, 0, stream>>>(emb, z, x, xh);
  csr_build<<<NG, 512, 0, stream>>>(ei, pos, offs, deg, csr);
  for (int l = 0; l < NL; l++) {
    gemm_proj<<<dim3(391, 8), 256, 0, stream>>>(xh, whT, P, l);
    edge_gather<<<NN / 4, 256, 0, stream>>>(P, csr, offs, deg, Wf, bf, Ws, bs, agg, l);
    col_stats<<<200, 256, 0, stream>>>(agg, x, partial);
    bn_coeffs<<<1, 128, 0, stream>>>(partial, bn1g, bn1b, bn2g, bn2b, abc, l);
    fuse_bn<<<2048, 256, 0, stream>>>(agg, x, xh, abc);
  }
  pool_mlp<<<NG, 512, 0, stream>>>(x, W1, b1, W2, b2, out);
}